// Round 1
// baseline (144.970 us; speedup 1.0000x reference)
//
#include <hip/hip_runtime.h>
#include <cfloat>

// Problem constants (match reference setup_inputs)
#define BB 4
#define NQ 8192
#define NK 2048
#define CC 128
#define KNN 3

#define QPB 64                 // queries per block
#define SPLITS 4               // key-range splits (one wave each)
#define KPS (NK / SPLITS)      // keys per split = 512
#define C4 (CC / 4)            // float4s per feature row = 32

// ---------------------------------------------------------------------------
// Kernel 1: pack keys as float4 {x, y, z, |k|^2} into workspace
// ---------------------------------------------------------------------------
__global__ __launch_bounds__(256) void pack_keys(
    const float* __restrict__ xyz_k, float4* __restrict__ keys)
{
    int i = blockIdx.x * 256 + threadIdx.x;   // flat b*NK + k
    if (i < BB * NK) {
        float x = xyz_k[i * 3 + 0];
        float y = xyz_k[i * 3 + 1];
        float z = xyz_k[i * 3 + 2];
        keys[i] = make_float4(x, y, z, fmaf(x, x, fmaf(y, y, z * z)));
    }
}

// ---------------------------------------------------------------------------
// Kernel 2: fused kNN + inverse-distance-weighted feature interpolation
//   grid = (NQ/QPB, BB), block = 256 = QPB queries x SPLITS splits
// ---------------------------------------------------------------------------
__global__ __launch_bounds__(256) void fp_main(
    const float*  __restrict__ xyz_q,
    const float4* __restrict__ keys,
    const float4* __restrict__ vk,
    float4*       __restrict__ out)
{
    __shared__ int   ci[SPLITS * QPB][4];   // per (split,query) top-4 candidate idx
    __shared__ float sw[QPB][4];            // final weights (3 used)
    __shared__ int   si[QPB][4];            // final indices (3 used)

    const int b     = blockIdx.y;
    const int qbase = blockIdx.x * QPB;
    const int lane  = threadIdx.x & 63;     // query within block
    const int split = threadIdx.x >> 6;     // which key range this wave scans
    const int q     = qbase + lane;

    // ---- load query coords (every split-thread of a query loads the same) ----
    const float qx = xyz_q[(b * NQ + q) * 3 + 0];
    const float qy = xyz_q[(b * NQ + q) * 3 + 1];
    const float qz = xyz_q[(b * NQ + q) * 3 + 2];
    // rank value t = |k|^2 - 2 q.k  (monotone in true distance per query)
    const float ax = -2.0f * qx, ay = -2.0f * qy, az = -2.0f * qz;

    // ---- phase 1: fp32 scan, keep top-4 per split ----
    // force wave-uniform scalar base so key loads are uniform/broadcast
    const int kbeg = __builtin_amdgcn_readfirstlane(split * KPS);
    const float4* kp = keys + b * NK + kbeg;

    float d0 = FLT_MAX, d1 = FLT_MAX, d2 = FLT_MAX, d3 = FLT_MAX;
    int   i0 = 0, i1 = 0, i2 = 0, i3 = 0;

    #pragma unroll 4
    for (int j = 0; j < KPS; ++j) {
        float4 kk = kp[j];
        float t = fmaf(ax, kk.x, fmaf(ay, kk.y, fmaf(az, kk.z, kk.w)));
        if (t < d3) {                       // rare after warm-up
            int kidx = kbeg + j;
            if (t < d1) {
                d3 = d2; i3 = i2; d2 = d1; i2 = i1;
                if (t < d0) { d1 = d0; i1 = i0; d0 = t; i0 = kidx; }
                else        { d1 = t;  i1 = kidx; }
            } else {
                if (t < d2) { d3 = d2; i3 = i2; d2 = t; i2 = kidx; }
                else        { d3 = t;  i3 = kidx; }
            }
        }
    }
    {
        int row = split * QPB + lane;
        ci[row][0] = i0; ci[row][1] = i1; ci[row][2] = i2; ci[row][3] = i3;
    }
    __syncthreads();

    // ---- phase 2: fp64 exact refine of 16 candidates (wave 0 only) ----
    if (threadIdx.x < QPB) {
        double e0 = DBL_MAX, e1 = DBL_MAX, e2 = DBL_MAX;
        int    j0 = 0, j1 = 0, j2 = 0;
        #pragma unroll
        for (int s = 0; s < SPLITS; ++s) {
            #pragma unroll
            for (int p = 0; p < 4; ++p) {
                int ki = ci[s * QPB + lane][p];
                float4 kk = keys[b * NK + ki];
                // exact for fp32 inputs: diffs exact in fp64, squares exact (48-bit)
                double dx = (double)qx - (double)kk.x;
                double dy = (double)qy - (double)kk.y;
                double dz = (double)qz - (double)kk.z;
                double dd = dx * dx + dy * dy + dz * dz;
                if (dd < e2) {
                    if (dd < e1) {
                        e2 = e1; j2 = j1;
                        if (dd < e0) { e1 = e0; j1 = j0; e0 = dd; j0 = ki; }
                        else         { e1 = dd; j1 = ki; }
                    } else { e2 = dd; j2 = ki; }
                }
            }
        }
        // reference: maximum(dist, 1e-10), inverse-distance weights, normalize
        e0 = e0 < 1e-10 ? 1e-10 : e0;
        e1 = e1 < 1e-10 ? 1e-10 : e1;
        e2 = e2 < 1e-10 ? 1e-10 : e2;
        double w0 = 1.0 / e0, w1 = 1.0 / e1, w2 = 1.0 / e2;
        double s  = w0 + w1 + w2;
        sw[lane][0] = (float)(w0 / s);
        sw[lane][1] = (float)(w1 / s);
        sw[lane][2] = (float)(w2 / s);
        si[lane][0] = j0; si[lane][1] = j1; si[lane][2] = j2;
    }
    __syncthreads();

    // ---- phase 3: gather + weighted sum, coalesced float4 writes ----
    const float4* vb = vk + (size_t)b * NK * C4;
    float4* ob = out + ((size_t)b * NQ + qbase) * C4;
    #pragma unroll
    for (int r = 0; r < (QPB * C4) / 256; ++r) {   // 8 iters
        int o  = r * 256 + threadIdx.x;
        int qq = o >> 5;          // C4 = 32 float4 per query
        int c4 = o & (C4 - 1);
        float w0 = sw[qq][0], w1 = sw[qq][1], w2 = sw[qq][2];
        int   j0 = si[qq][0], j1 = si[qq][1], j2 = si[qq][2];
        float4 v0 = vb[j0 * C4 + c4];
        float4 v1 = vb[j1 * C4 + c4];
        float4 v2 = vb[j2 * C4 + c4];
        float4 res;
        res.x = fmaf(w0, v0.x, fmaf(w1, v1.x, w2 * v2.x));
        res.y = fmaf(w0, v0.y, fmaf(w1, v1.y, w2 * v2.y));
        res.z = fmaf(w0, v0.z, fmaf(w1, v1.z, w2 * v2.z));
        res.w = fmaf(w0, v0.w, fmaf(w1, v1.w, w2 * v2.w));
        ob[o] = res;
    }
}

// ---------------------------------------------------------------------------
extern "C" void kernel_launch(void* const* d_in, const int* in_sizes, int n_in,
                              void* d_out, int out_size, void* d_ws, size_t ws_size,
                              hipStream_t stream)
{
    const float* xyz_q = (const float*)d_in[0];
    const float* xyz_k = (const float*)d_in[1];
    const float* v_k   = (const float*)d_in[2];

    float4* keys = (float4*)d_ws;   // BB*NK float4 = 128 KiB

    pack_keys<<<dim3((BB * NK + 255) / 256), dim3(256), 0, stream>>>(xyz_k, keys);
    fp_main<<<dim3(NQ / QPB, BB), dim3(256), 0, stream>>>(
        xyz_q, keys, (const float4*)v_k, (float4*)d_out);
}

// Round 2
// 91.364 us; speedup vs baseline: 1.5867x; 1.5867x over previous
//
#include <hip/hip_runtime.h>
#include <cfloat>

// Problem constants (match reference setup_inputs)
#define BB 4
#define NQ 8192
#define NK 2048
#define CC 128
#define C4 (CC / 4)            // 32 float4 per feature row

#define QPB 64                 // queries per block (= lane id)
#define SPLITS 16              // key splits, one wave each (wave-uniform)
#define KPS (NK / SPLITS)      // 128 keys per split (local idx fits 7 bits)
#define NTHR (QPB * SPLITS)    // 1024 threads per block

static __device__ __forceinline__ unsigned umin32(unsigned a, unsigned b) { return a < b ? a : b; }
static __device__ __forceinline__ unsigned umax32(unsigned a, unsigned b) { return a > b ? a : b; }

// ---------------------------------------------------------------------------
// Fused: kNN (branchless packed top-4 per split, fp64 refine) + interpolation
//   grid = (NQ/QPB, BB), block = 1024 = 64 queries x 16 splits
// ---------------------------------------------------------------------------
__global__ __launch_bounds__(NTHR, 8) void fp_fused(
    const float*  __restrict__ xyz_q,
    const float*  __restrict__ xyz_k,
    const float4* __restrict__ vk,
    float4*       __restrict__ out)
{
    // packed fp64 candidates: (bits(dd) & ~0x7FF) | global_kidx  (11 bits)
    __shared__ unsigned long long rd[NTHR][4];   // 32 KiB
    __shared__ float sw[QPB][4];
    __shared__ int   si[QPB][4];

    const int b     = blockIdx.y;
    const int qbase = blockIdx.x * QPB;
    const int tid   = threadIdx.x;
    const int lane  = tid & 63;                  // query within block
    const int split = tid >> 6;                  // wave id == key split (uniform)
    const int q     = qbase + lane;

    const float qx = xyz_q[(b * NQ + q) * 3 + 0];
    const float qy = xyz_q[(b * NQ + q) * 3 + 1];
    const float qz = xyz_q[(b * NQ + q) * 3 + 2];

    // wave-uniform key range -> scalar loads on the SMEM pipe
    const int kbeg = __builtin_amdgcn_readfirstlane(split * KPS);
    const float* kp = xyz_k + ((size_t)b * NK + kbeg) * 3;

    // ---- phase 1: branchless fp32 scan, packed top-4 (sorted min-network) ----
    unsigned u0 = 0xFFFFFFFFu, u1 = 0xFFFFFFFFu, u2 = 0xFFFFFFFFu, u3 = 0xFFFFFFFFu;

    #pragma unroll 4
    for (int j = 0; j < KPS; ++j) {
        float kx = kp[j * 3 + 0];
        float ky = kp[j * 3 + 1];
        float kz = kp[j * 3 + 2];
        float dx = qx - kx, dy = qy - ky, dz = qz - kz;
        float t = fmaf(dx, dx, fmaf(dy, dy, dz * dz));   // >= 0 always
        // keep 17 significant dist bits, low 7 bits = local key index
        unsigned p = (__float_as_uint(t) & 0xFFFFFF80u) | (unsigned)j;
        // sorted insert into (u0<=u1<=u2<=u3), pure min/max
        unsigned m2 = umax32(p, u2), m1 = umax32(p, u1), m0 = umax32(p, u0);
        u3 = umin32(u3, m2);
        u2 = umin32(u2, m1);
        u1 = umin32(u1, m0);
        u0 = umin32(u0, p);
    }

    // ---- phase 2a: every thread fp64-refines its own 4 candidates ----
    {
        unsigned uu[4] = { u0, u1, u2, u3 };
        #pragma unroll
        for (int c = 0; c < 4; ++c) {
            int kidx = kbeg + (int)(uu[c] & 0x7Fu);
            const float* ka = xyz_k + ((size_t)b * NK + kidx) * 3;
            double dx = (double)qx - (double)ka[0];
            double dy = (double)qy - (double)ka[1];
            double dz = (double)qz - (double)ka[2];
            double dd = dx * dx + dy * dy + dz * dz;   // exact ordering for fp32 inputs
            unsigned long long pk =
                (((unsigned long long)__double_as_longlong(dd)) & ~0x7FFull)
                | (unsigned long long)kidx;
            rd[tid][c] = pk;
        }
    }
    __syncthreads();

    // ---- phase 2b: wave 0 selects exact top-3 of 64 candidates per query ----
    if (tid < QPB) {
        // packed uint64s reinterpreted as positive doubles stay order-correct
        double m0 = DBL_MAX, m1 = DBL_MAX, m2 = DBL_MAX;
        #pragma unroll 4
        for (int s = 0; s < SPLITS; ++s) {
            #pragma unroll
            for (int c = 0; c < 4; ++c) {
                double x = __longlong_as_double((long long)rd[s * QPB + lane][c]);
                double a1 = fmax(x, m1), a0 = fmax(x, m0);
                m2 = fmin(m2, a1);
                m1 = fmin(m1, a0);
                m0 = fmin(m0, x);
            }
        }
        unsigned long long b0 = (unsigned long long)__double_as_longlong(m0);
        unsigned long long b1 = (unsigned long long)__double_as_longlong(m1);
        unsigned long long b2 = (unsigned long long)__double_as_longlong(m2);
        double e0 = __longlong_as_double((long long)(b0 & ~0x7FFull));
        double e1 = __longlong_as_double((long long)(b1 & ~0x7FFull));
        double e2 = __longlong_as_double((long long)(b2 & ~0x7FFull));
        e0 = fmax(e0, 1e-10);
        e1 = fmax(e1, 1e-10);
        e2 = fmax(e2, 1e-10);
        double w0 = 1.0 / e0, w1 = 1.0 / e1, w2 = 1.0 / e2;
        double s  = w0 + w1 + w2;
        sw[lane][0] = (float)(w0 / s);
        sw[lane][1] = (float)(w1 / s);
        sw[lane][2] = (float)(w2 / s);
        si[lane][0] = (int)(b0 & 0x7FFull);
        si[lane][1] = (int)(b1 & 0x7FFull);
        si[lane][2] = (int)(b2 & 0x7FFull);
    }
    __syncthreads();

    // ---- phase 3: gather + weighted sum, coalesced float4 writes ----
    const float4* vb = vk + (size_t)b * NK * C4;
    float4* ob = out + ((size_t)b * NQ + qbase) * C4;
    #pragma unroll
    for (int r = 0; r < (QPB * C4) / NTHR; ++r) {   // 2 iters
        int o  = r * NTHR + tid;
        int qq = o >> 5;          // C4 = 32 float4 per query
        int c4 = o & (C4 - 1);
        float w0 = sw[qq][0], w1 = sw[qq][1], w2 = sw[qq][2];
        int   j0 = si[qq][0], j1 = si[qq][1], j2 = si[qq][2];
        float4 v0 = vb[j0 * C4 + c4];
        float4 v1 = vb[j1 * C4 + c4];
        float4 v2 = vb[j2 * C4 + c4];
        float4 res;
        res.x = fmaf(w0, v0.x, fmaf(w1, v1.x, w2 * v2.x));
        res.y = fmaf(w0, v0.y, fmaf(w1, v1.y, w2 * v2.y));
        res.z = fmaf(w0, v0.z, fmaf(w1, v1.z, w2 * v2.z));
        res.w = fmaf(w0, v0.w, fmaf(w1, v1.w, w2 * v2.w));
        ob[o] = res;
    }
}

// ---------------------------------------------------------------------------
extern "C" void kernel_launch(void* const* d_in, const int* in_sizes, int n_in,
                              void* d_out, int out_size, void* d_ws, size_t ws_size,
                              hipStream_t stream)
{
    const float* xyz_q = (const float*)d_in[0];
    const float* xyz_k = (const float*)d_in[1];
    const float* v_k   = (const float*)d_in[2];

    fp_fused<<<dim3(NQ / QPB, BB), dim3(NTHR), 0, stream>>>(
        xyz_q, xyz_k, (const float4*)v_k, (float4*)d_out);
}

// Round 3
// 89.338 us; speedup vs baseline: 1.6227x; 1.0227x over previous
//
#include <hip/hip_runtime.h>
#include <cfloat>

// Problem constants (match reference setup_inputs)
#define BB 4
#define NQ 8192
#define NK 2048
#define CC 128
#define C4 (CC / 4)            // 32 float4 per feature row

#define QPB 64                 // queries per block (= lane id)
#define SPLITS 16              // key splits, one wave each (wave-uniform)
#define KPS (NK / SPLITS)      // 128 keys per split (local idx fits 7 bits)
#define NTHR (QPB * SPLITS)    // 1024 threads per block

// ---------------------------------------------------------------------------
// Fused: kNN (branchless packed top-4 per split via v_med3, fp64 refine)
//        + inverse-distance-weighted interpolation
//   grid = (NQ/QPB, BB), block = 1024 = 64 queries x 16 splits
// ---------------------------------------------------------------------------
__global__ __launch_bounds__(NTHR, 8) void fp_fused(
    const float*  __restrict__ xyz_q,
    const float*  __restrict__ xyz_k,
    const float4* __restrict__ vk,
    float4*       __restrict__ out)
{
    // packed fp64 candidates: (bits(dd) & ~0x7FF) | global_kidx  (11 bits)
    __shared__ unsigned long long rd[NTHR][4];   // 32 KiB
    __shared__ float sw[QPB][4];
    __shared__ int   si[QPB][4];

    const int b     = blockIdx.y;
    const int qbase = blockIdx.x * QPB;
    const int tid   = threadIdx.x;
    const int lane  = tid & 63;                  // query within block
    const int split = tid >> 6;                  // wave id == key split (uniform)
    const int q     = qbase + lane;

    const float qx = xyz_q[(b * NQ + q) * 3 + 0];
    const float qy = xyz_q[(b * NQ + q) * 3 + 1];
    const float qz = xyz_q[(b * NQ + q) * 3 + 2];

    // wave-uniform key range -> scalar (SMEM) loads
    const int kbeg = __builtin_amdgcn_readfirstlane(split * KPS);
    const float* kp = xyz_k + ((size_t)b * NK + kbeg) * 3;

    // ---- phase 1: branchless fp32 scan, packed top-4 via med3 insert ----
    // invariant: u0 <= u1 <= u2 <= u3 (positive floats, low 7 bits = local idx)
    float u0 = FLT_MAX, u1 = FLT_MAX, u2 = FLT_MAX, u3 = FLT_MAX;

    #pragma unroll 8
    for (int j = 0; j < KPS; ++j) {
        float kx = kp[j * 3 + 0];
        float ky = kp[j * 3 + 1];
        float kz = kp[j * 3 + 2];
        float dx = qx - kx, dy = qy - ky, dz = qz - kz;
        float t = fmaf(dx, dx, fmaf(dy, dy, dz * dz));   // >= 0 structurally
        // v_and_or_b32: keep 17 significant dist bits, low 7 = local key index
        float p = __uint_as_float((__float_as_uint(t) & 0xFFFFFF80u) | (unsigned)j);
        // sorted insert, 4 ops (3x v_med3_f32 + v_min_f32)
        u3 = __builtin_amdgcn_fmed3f(p, u2, u3);
        u2 = __builtin_amdgcn_fmed3f(p, u1, u2);
        u1 = __builtin_amdgcn_fmed3f(p, u0, u1);
        u0 = fminf(u0, p);
    }

    // ---- phase 2a: every thread fp64-refines its own 4 candidates ----
    {
        float uu[4] = { u0, u1, u2, u3 };
        #pragma unroll
        for (int c = 0; c < 4; ++c) {
            int kidx = kbeg + (int)(__float_as_uint(uu[c]) & 0x7Fu);
            const float* ka = xyz_k + ((size_t)b * NK + kidx) * 3;
            double dx = (double)qx - (double)ka[0];
            double dy = (double)qy - (double)ka[1];
            double dz = (double)qz - (double)ka[2];
            double dd = dx * dx + dy * dy + dz * dz;   // exact ordering for fp32 inputs
            unsigned long long pk =
                (((unsigned long long)__double_as_longlong(dd)) & ~0x7FFull)
                | (unsigned long long)kidx;
            rd[tid][c] = pk;
        }
    }
    __syncthreads();

    // ---- phase 2b: wave 0 selects exact top-3 of 64 candidates per query ----
    if (tid < QPB) {
        // packed uint64s reinterpreted as positive doubles stay order-correct
        double m0 = DBL_MAX, m1 = DBL_MAX, m2 = DBL_MAX;
        #pragma unroll 4
        for (int s = 0; s < SPLITS; ++s) {
            #pragma unroll
            for (int c = 0; c < 4; ++c) {
                double x = __longlong_as_double((long long)rd[s * QPB + lane][c]);
                double a1 = fmax(x, m1), a0 = fmax(x, m0);
                m2 = fmin(m2, a1);
                m1 = fmin(m1, a0);
                m0 = fmin(m0, x);
            }
        }
        unsigned long long b0 = (unsigned long long)__double_as_longlong(m0);
        unsigned long long b1 = (unsigned long long)__double_as_longlong(m1);
        unsigned long long b2 = (unsigned long long)__double_as_longlong(m2);
        double e0 = __longlong_as_double((long long)(b0 & ~0x7FFull));
        double e1 = __longlong_as_double((long long)(b1 & ~0x7FFull));
        double e2 = __longlong_as_double((long long)(b2 & ~0x7FFull));
        e0 = fmax(e0, 1e-10);
        e1 = fmax(e1, 1e-10);
        e2 = fmax(e2, 1e-10);
        double w0 = 1.0 / e0, w1 = 1.0 / e1, w2 = 1.0 / e2;
        double s  = w0 + w1 + w2;
        sw[lane][0] = (float)(w0 / s);
        sw[lane][1] = (float)(w1 / s);
        sw[lane][2] = (float)(w2 / s);
        si[lane][0] = (int)(b0 & 0x7FFull);
        si[lane][1] = (int)(b1 & 0x7FFull);
        si[lane][2] = (int)(b2 & 0x7FFull);
    }
    __syncthreads();

    // ---- phase 3: gather + weighted sum, coalesced float4 writes ----
    const float4* vb = vk + (size_t)b * NK * C4;
    float4* ob = out + ((size_t)b * NQ + qbase) * C4;
    #pragma unroll
    for (int r = 0; r < (QPB * C4) / NTHR; ++r) {   // 2 iters
        int o  = r * NTHR + tid;
        int qq = o >> 5;          // C4 = 32 float4 per query
        int c4 = o & (C4 - 1);
        float w0 = sw[qq][0], w1 = sw[qq][1], w2 = sw[qq][2];
        int   j0 = si[qq][0], j1 = si[qq][1], j2 = si[qq][2];
        float4 v0 = vb[j0 * C4 + c4];
        float4 v1 = vb[j1 * C4 + c4];
        float4 v2 = vb[j2 * C4 + c4];
        float4 res;
        res.x = fmaf(w0, v0.x, fmaf(w1, v1.x, w2 * v2.x));
        res.y = fmaf(w0, v0.y, fmaf(w1, v1.y, w2 * v2.y));
        res.z = fmaf(w0, v0.z, fmaf(w1, v1.z, w2 * v2.z));
        res.w = fmaf(w0, v0.w, fmaf(w1, v1.w, w2 * v2.w));
        ob[o] = res;
    }
}

// ---------------------------------------------------------------------------
extern "C" void kernel_launch(void* const* d_in, const int* in_sizes, int n_in,
                              void* d_out, int out_size, void* d_ws, size_t ws_size,
                              hipStream_t stream)
{
    const float* xyz_q = (const float*)d_in[0];
    const float* xyz_k = (const float*)d_in[1];
    const float* v_k   = (const float*)d_in[2];

    fp_fused<<<dim3(NQ / QPB, BB), dim3(NTHR), 0, stream>>>(
        xyz_q, xyz_k, (const float4*)v_k, (float4*)d_out);
}

// Round 4
// 89.205 us; speedup vs baseline: 1.6251x; 1.0015x over previous
//
#include <hip/hip_runtime.h>
#include <cfloat>

// Problem constants (match reference setup_inputs)
#define BB 4
#define NQ 8192
#define NK 2048
#define CC 128
#define C4 (CC / 4)            // 32 float4 per feature row

#define QPB 64                 // queries per block (= lane id)
#define SPLITS 16              // key splits, one wave each (wave-uniform)
#define KPS (NK / SPLITS)      // 128 keys per split (local idx fits 7 bits)
#define NTHR (QPB * SPLITS)    // 1024 threads per block

// ---------------------------------------------------------------------------
// Fused: kNN (branchless packed top-4 per split via v_med3, fp64 refine)
//        + inverse-distance-weighted interpolation
//   grid = (NQ/QPB, BB), block = 1024 = 64 queries x 16 splits
//   Keys staged in LDS: wave-uniform ds_read_b128 = HW broadcast, avoiding
//   per-lane global_load address-processing (the round-3 bottleneck theory).
// ---------------------------------------------------------------------------
__global__ __launch_bounds__(NTHR, 8) void fp_fused(
    const float*  __restrict__ xyz_q,
    const float*  __restrict__ xyz_k,
    const float4* __restrict__ vk,
    float4*       __restrict__ out)
{
    __shared__ float4 ks[NK];                    // 32 KiB: {x,y,z,0} per key
    // packed fp64 candidates: (bits(dd) & ~0x7FF) | global_kidx  (11 bits)
    __shared__ unsigned long long rd[NTHR][4];   // 32 KiB
    __shared__ float sw[QPB][4];
    __shared__ int   si[QPB][4];

    const int b     = blockIdx.y;
    const int qbase = blockIdx.x * QPB;
    const int tid   = threadIdx.x;
    const int lane  = tid & 63;                  // query within block
    const int split = tid >> 6;                  // wave id == key split (uniform)
    const int q     = qbase + lane;

    // ---- stage this batch's keys into LDS (coalesced, 2 keys/thread) ----
    {
        const float* kb = xyz_k + (size_t)b * NK * 3;
        #pragma unroll
        for (int i = tid; i < NK; i += NTHR) {
            ks[i] = make_float4(kb[i * 3 + 0], kb[i * 3 + 1], kb[i * 3 + 2], 0.0f);
        }
    }

    const float qx = xyz_q[(b * NQ + q) * 3 + 0];
    const float qy = xyz_q[(b * NQ + q) * 3 + 1];
    const float qz = xyz_q[(b * NQ + q) * 3 + 2];

    __syncthreads();

    // wave-uniform key range
    const int kbeg = __builtin_amdgcn_readfirstlane(split * KPS);

    // ---- phase 1: branchless fp32 scan, packed top-4 via med3 insert ----
    // invariant: u0 <= u1 <= u2 <= u3 (positive floats, low 7 bits = local idx)
    float u0 = FLT_MAX, u1 = FLT_MAX, u2 = FLT_MAX, u3 = FLT_MAX;

    #pragma unroll 8
    for (int j = 0; j < KPS; ++j) {
        float4 kk = ks[kbeg + j];                // uniform addr -> LDS broadcast
        float dx = qx - kk.x, dy = qy - kk.y, dz = qz - kk.z;
        float t = fmaf(dx, dx, fmaf(dy, dy, dz * dz));   // >= 0 structurally
        // v_and_or_b32: keep 17 significant dist bits, low 7 = local key index
        float p = __uint_as_float((__float_as_uint(t) & 0xFFFFFF80u) | (unsigned)j);
        // sorted insert, 4 ops (3x v_med3_f32 + v_min_f32)
        u3 = __builtin_amdgcn_fmed3f(p, u2, u3);
        u2 = __builtin_amdgcn_fmed3f(p, u1, u2);
        u1 = __builtin_amdgcn_fmed3f(p, u0, u1);
        u0 = fminf(u0, p);
    }

    // ---- phase 2a: every thread fp64-refines its own 4 candidates ----
    {
        float uu[4] = { u0, u1, u2, u3 };
        #pragma unroll
        for (int c = 0; c < 4; ++c) {
            int kidx = kbeg + (int)(__float_as_uint(uu[c]) & 0x7Fu);
            float4 ka = ks[kidx];                // LDS gather (4 reads, cheap)
            double dx = (double)qx - (double)ka.x;
            double dy = (double)qy - (double)ka.y;
            double dz = (double)qz - (double)ka.z;
            double dd = dx * dx + dy * dy + dz * dz;   // exact ordering for fp32 inputs
            unsigned long long pk =
                (((unsigned long long)__double_as_longlong(dd)) & ~0x7FFull)
                | (unsigned long long)kidx;
            rd[tid][c] = pk;
        }
    }
    __syncthreads();

    // ---- phase 2b: wave 0 selects exact top-3 of 64 candidates per query ----
    if (tid < QPB) {
        // packed uint64s reinterpreted as positive doubles stay order-correct
        double m0 = DBL_MAX, m1 = DBL_MAX, m2 = DBL_MAX;
        #pragma unroll 4
        for (int s = 0; s < SPLITS; ++s) {
            #pragma unroll
            for (int c = 0; c < 4; ++c) {
                double x = __longlong_as_double((long long)rd[s * QPB + lane][c]);
                double a1 = fmax(x, m1), a0 = fmax(x, m0);
                m2 = fmin(m2, a1);
                m1 = fmin(m1, a0);
                m0 = fmin(m0, x);
            }
        }
        unsigned long long b0 = (unsigned long long)__double_as_longlong(m0);
        unsigned long long b1 = (unsigned long long)__double_as_longlong(m1);
        unsigned long long b2 = (unsigned long long)__double_as_longlong(m2);
        double e0 = __longlong_as_double((long long)(b0 & ~0x7FFull));
        double e1 = __longlong_as_double((long long)(b1 & ~0x7FFull));
        double e2 = __longlong_as_double((long long)(b2 & ~0x7FFull));
        e0 = fmax(e0, 1e-10);
        e1 = fmax(e1, 1e-10);
        e2 = fmax(e2, 1e-10);
        double w0 = 1.0 / e0, w1 = 1.0 / e1, w2 = 1.0 / e2;
        double s  = w0 + w1 + w2;
        sw[lane][0] = (float)(w0 / s);
        sw[lane][1] = (float)(w1 / s);
        sw[lane][2] = (float)(w2 / s);
        si[lane][0] = (int)(b0 & 0x7FFull);
        si[lane][1] = (int)(b1 & 0x7FFull);
        si[lane][2] = (int)(b2 & 0x7FFull);
    }
    __syncthreads();

    // ---- phase 3: gather + weighted sum, coalesced float4 writes ----
    const float4* vb = vk + (size_t)b * NK * C4;
    float4* ob = out + ((size_t)b * NQ + qbase) * C4;
    #pragma unroll
    for (int r = 0; r < (QPB * C4) / NTHR; ++r) {   // 2 iters
        int o  = r * NTHR + tid;
        int qq = o >> 5;          // C4 = 32 float4 per query
        int c4 = o & (C4 - 1);
        float w0 = sw[qq][0], w1 = sw[qq][1], w2 = sw[qq][2];
        int   j0 = si[qq][0], j1 = si[qq][1], j2 = si[qq][2];
        float4 v0 = vb[j0 * C4 + c4];
        float4 v1 = vb[j1 * C4 + c4];
        float4 v2 = vb[j2 * C4 + c4];
        float4 res;
        res.x = fmaf(w0, v0.x, fmaf(w1, v1.x, w2 * v2.x));
        res.y = fmaf(w0, v0.y, fmaf(w1, v1.y, w2 * v2.y));
        res.z = fmaf(w0, v0.z, fmaf(w1, v1.z, w2 * v2.z));
        res.w = fmaf(w0, v0.w, fmaf(w1, v1.w, w2 * v2.w));
        ob[o] = res;
    }
}

// ---------------------------------------------------------------------------
extern "C" void kernel_launch(void* const* d_in, const int* in_sizes, int n_in,
                              void* d_out, int out_size, void* d_ws, size_t ws_size,
                              hipStream_t stream)
{
    const float* xyz_q = (const float*)d_in[0];
    const float* xyz_k = (const float*)d_in[1];
    const float* v_k   = (const float*)d_in[2];

    fp_fused<<<dim3(NQ / QPB, BB), dim3(NTHR), 0, stream>>>(
        xyz_q, xyz_k, (const float4*)v_k, (float4*)d_out);
}